// Round 20
// baseline (71.860 us; speedup 1.0000x reference)
//
#include <hip/hip_runtime.h>
#include <stdint.h>

// Bitnet int8 x int2 GEMM: C[M,N](i32) = A[M,K](i8) . W[N,K]^T
// Round 20: R14/R19 producer-consumer + cross-barrier consumer register
// pipeline. Producer certifies stages <= k+1 at barrier #k (PWAIT(10));
// consumers issue ds_reads for step t+1 right after barrier #t+1 and
// compute step t from registers -- LDS burst overlaps the MFMA cluster.
// Ring (4 x 10 KB), producer addressing, fetch pattern identical to R14.

#define MM 1024
#define NN 11008
#define KK 4096
#define MTILES 8
#define NTILES 86
#define NBLOCKS (MTILES * NTILES)          // 688
#define STRIDE_A ((size_t)MTILES * 8192)   // A2 bytes per kstep (64)
#define STRIDE_B ((size_t)NTILES * 2048)   // B3 bytes per kstep

using i32x4  = __attribute__((ext_vector_type(4))) int;
using i32x16 = __attribute__((ext_vector_type(16))) int;

__device__ __forceinline__ int pack4(i32x4 v) {
    return (int)(((uint32_t)v[0] & 0xFFu) | (((uint32_t)v[1] & 0xFFu) << 8)
               | (((uint32_t)v[2] & 0xFFu) << 16) | (((uint32_t)v[3] & 0xFFu) << 24));
}

// Fused prepass (R19 version: A unchanged, B write-coalesced). Proven absmax=0.
__global__ __launch_bounds__(256) void prep_AB(const int* __restrict__ Asrc,
                                               const int* __restrict__ Bsrc,
                                               uint8_t* __restrict__ A2,
                                               uint8_t* __restrict__ B3) {
    if (blockIdx.x < 1024) {
        const int g = blockIdx.x * 256 + threadIdx.x;    // < 262144
        const int kstep = g >> 12;
        const int rem   = g & 4095;
        const int mtile = rem >> 9;
        const int c     = rem & 511;
        const int row32 = (c >> 7) & 3, kk2 = (c >> 6) & 1;
        const int lane  = c & 63;
        const int row   = mtile * 128 + row32 * 32 + (lane & 31);
        const int kbyte = kstep * 64 + kk2 * 32 + (lane >> 5) * 16;
        const i32x4* s4 = (const i32x4*)(Asrc + (size_t)row * KK + kbyte);
        i32x4 o;
#pragma unroll
        for (int q = 0; q < 4; ++q) o[q] = pack4(s4[q]);
        *(i32x4*)(A2 + (size_t)g * 16) = o;
    } else {
        const int t = (blockIdx.x - 1024) * 256 + threadIdx.x;   // < 704512
        const int kstep = t / NN;
        const int n     = t - kstep * NN;
        const int ntile = n >> 7, hf = (n >> 6) & 1, ni = (n >> 5) & 1, l31 = n & 31;
        const i32x4* s4 = (const i32x4*)(Bsrc + (size_t)n * (KK / 4) + kstep * 16);
        int w[4];                       // j = kk2*2 + h
#pragma unroll
        for (int j = 0; j < 4; ++j) w[j] = pack4(s4[j]);
        uint8_t* base = B3 + ((size_t)kstep * NTILES + ntile) * 2048 + hf * 1024;
        *(int2*)(base + l31 * 16 + ni * 8)        = make_int2(w[0], w[2]);  // h=0
        *(int2*)(base + (l31 + 32) * 16 + ni * 8) = make_int2(w[1], w[3]);  // h=1
    }
}

#define GLOAD_LDS16(g, l) __builtin_amdgcn_global_load_lds(                    \
        (const __attribute__((address_space(1))) uint32_t*)(g),                \
        (__attribute__((address_space(3))) uint32_t*)(l), 16, 0, 0)

#define MFMA_I8 __builtin_amdgcn_mfma_i32_32x32x32_i8

// Producer: stage K-step T into slot T&3 (A 8 KB = 8 instrs, B 2 KB = 2).
#define PSTAGE(T) do {                                                         \
    const uint8_t* at_ = gA + (size_t)(T) * STRIDE_A;                          \
    const uint8_t* bt_ = gB + (size_t)(T) * STRIDE_B;                          \
    uint8_t* l_ = &As[(T) & 3][0];                                             \
    GLOAD_LDS16(at_,        l_);                                               \
    GLOAD_LDS16(at_ + 1024, l_ + 1024);                                        \
    GLOAD_LDS16(at_ + 2048, l_ + 2048);                                        \
    GLOAD_LDS16(at_ + 3072, l_ + 3072);                                        \
    GLOAD_LDS16(at_ + 4096, l_ + 4096);                                        \
    GLOAD_LDS16(at_ + 5120, l_ + 5120);                                        \
    GLOAD_LDS16(at_ + 6144, l_ + 6144);                                        \
    GLOAD_LDS16(at_ + 7168, l_ + 7168);                                        \
    GLOAD_LDS16(bt_,        l_ + 8192);                                        \
    GLOAD_LDS16(bt_ + 1024, l_ + 9216);                                        \
} while (0)

#define PWAIT(N) asm volatile("s_waitcnt vmcnt(" #N ")" ::: "memory")
#define BAR()    __builtin_amdgcn_s_barrier()

// Consumer: read step T's 5 fragment lines into register buffer BUF.
#define READF(BUF, T) do {                                                     \
    const uint8_t* ab_ = &As[(T) & 3][0];                                      \
    BUF##_a00 = *(const i32x4*)(ab_ + (wr * 2 + 0) * 2048 + lane * 16);        \
    BUF##_a01 = *(const i32x4*)(ab_ + (wr * 2 + 0) * 2048 + 1024 + lane * 16); \
    BUF##_a10 = *(const i32x4*)(ab_ + (wr * 2 + 1) * 2048 + lane * 16);        \
    BUF##_a11 = *(const i32x4*)(ab_ + (wr * 2 + 1) * 2048 + 1024 + lane * 16); \
    BUF##_bv  = *(const i32x4*)(ab_ + 8192 + wc * 1024 + lane * 16);           \
} while (0)

// Consumer: decode + 8 MFMA from register buffer BUF (no LDS access).
#define COMPR(BUF) do {                                                        \
    _Pragma("unroll")                                                          \
    for (int kk2_ = 0; kk2_ < 2; ++kk2_) {                                     \
        const uint32_t q0_ = (uint32_t)BUF##_bv[kk2_];                         \
        const uint32_t q1_ = (uint32_t)BUF##_bv[2 + kk2_];                     \
        i32x4 b0_, b1_;                                                        \
        _Pragma("unroll")                                                      \
        for (int i_ = 0; i_ < 4; ++i_) {                                       \
            b0_[i_] = (int)((q0_ >> (2 * i_)) & 0x03030303u);                  \
            b1_[i_] = (int)((q1_ >> (2 * i_)) & 0x03030303u);                  \
        }                                                                      \
        const i32x4 am0_ = kk2_ ? BUF##_a01 : BUF##_a00;                       \
        const i32x4 am1_ = kk2_ ? BUF##_a11 : BUF##_a10;                       \
        acc[0][0] = MFMA_I8(am0_, b0_, acc[0][0], 0, 0, 0);                    \
        acc[0][1] = MFMA_I8(am0_, b1_, acc[0][1], 0, 0, 0);                    \
        acc[1][0] = MFMA_I8(am1_, b0_, acc[1][0], 0, 0, 0);                    \
        acc[1][1] = MFMA_I8(am1_, b1_, acc[1][1], 0, 0, 0);                    \
    }                                                                          \
} while (0)

__global__ __launch_bounds__(320, 3) void bitnet_gemm(const uint8_t* __restrict__ A2,
                                                      const uint8_t* __restrict__ B3,
                                                      int* __restrict__ C) {
    const int tid  = threadIdx.x;
    const int lane = tid & 63, wave = tid >> 6;   // waves 0-3 consume, 4 produces
    const int wr   = (wave >> 1) & 1, wc = wave & 1;
    const int l31  = lane & 31, h = lane >> 5;

    // bijective XCD swizzle (688 = 8*86), bm fastest within an XCD chunk.
    const int bid = blockIdx.x;
    const int l   = (bid & 7) * (NBLOCKS / 8) + (bid >> 3);
    const int bm  = l & 7;       // 128-row tile 0..7
    const int bn  = l >> 3;      // 128-col tile 0..85

    __shared__ __align__(16) uint8_t As[4][10240];   // 40 KiB ring

    if (wave == 4) {
        // ------- producer: 65 barriers; at barrier #k stages <= k+1 done ----
        const uint8_t* gA = A2 + (size_t)bm * 8192 + lane * 16;
        const uint8_t* gB = B3 + (size_t)bn * 2048 + lane * 16;

        PSTAGE(0); PSTAGE(1); PSTAGE(2);   // 30 outstanding
        PWAIT(10);                         // stages 0,1 resident
        BAR();                             // barrier #0
#pragma unroll 1
        for (int t = 0; t < 60; t += 4) {
            PSTAGE(t + 3); PWAIT(10); BAR();   // #t+1: stages <= t+2 done
            PSTAGE(t + 4); PWAIT(10); BAR();
            PSTAGE(t + 5); PWAIT(10); BAR();
            PSTAGE(t + 6); PWAIT(10); BAR();
        }
        PSTAGE(63); PWAIT(10); BAR();      // #61: stages <= 62 done
        PWAIT(0);  BAR();                  // #62: stage 63 done
        BAR();                             // #63
        BAR();                             // #64
        return;
    }

    // ------- consumers: 65 barriers; prefetch t+1 regs, compute t ----------
    i32x16 acc[2][2] = {};
    i32x4 b0_a00, b0_a01, b0_a10, b0_a11, b0_bv;
    i32x4 b1_a00, b1_a01, b1_a10, b1_a11, b1_bv;

    BAR();            // #0: stages 0,1 resident
    READF(b0, 0);

#pragma unroll 1
    for (int t = 0; t < 62; t += 2) {
        BAR();                 // #t+1: stage t+1 certified
        READF(b1, t + 1);      // ds_reads overlap COMPR's MFMA cluster
        COMPR(b0);
        BAR();                 // #t+2: stage t+2 certified
        READF(b0, t + 2);
        COMPR(b1);
    }
    BAR();                     // #63
    READF(b1, 63);
    COMPR(b0);                 // step 62
    BAR();                     // #64
    COMPR(b1);                 // step 63

    // C write: col = lane&31, row = (r&3) + 8*(r>>2) + 4*(lane>>5)
    const int brow = bm * 128, bcol = bn * 128;
#pragma unroll
    for (int mi = 0; mi < 2; ++mi)
#pragma unroll
        for (int ni = 0; ni < 2; ++ni) {
            const int colg = bcol + wc * 64 + ni * 32 + l31;
#pragma unroll
            for (int r = 0; r < 16; ++r) {
                const int rowin = (r & 3) + 8 * (r >> 2) + 4 * h;
                const int rowg  = brow + wr * 64 + mi * 32 + rowin;
                C[(size_t)rowg * NN + colg] = acc[mi][ni][r];
            }
        }
}

extern "C" void kernel_launch(void* const* d_in, const int* in_sizes, int n_in,
                              void* d_out, int out_size, void* d_ws, size_t ws_size,
                              hipStream_t stream) {
    const int* A32 = (const int*)d_in[0];   // [M,K] int8 values in int32
    const int* B32 = (const int*)d_in[1];   // [N,K/4] packed bytes in int32
    int* C = (int*)d_out;                   // [M,N] int32

    uint8_t* A2 = (uint8_t*)d_ws;                      // 4 MiB
    uint8_t* B3 = A2 + (size_t)MM * KK;                // 10.75 MiB

    prep_AB<<<dim3(1024 + 2752), dim3(256), 0, stream>>>(A32, B32, A2, B3);
    bitnet_gemm<<<dim3(NBLOCKS), dim3(320), 0, stream>>>(A2, B3, C);
}

// Round 21
// 63.635 us; speedup vs baseline: 1.1293x; 1.1293x over previous
//
#include <hip/hip_runtime.h>
#include <stdint.h>

// Bitnet int8 x int2 GEMM: C[M,N](i32) = A[M,K](i8) . W[N,K]^T
// Round 21 (final): revert to the empirically best passing configuration —
// R14 verbatim. 688 blocks x 5 waves: waves 0-3 consume (2x2 of 64x64,
// ds_read+decode+MFMA only), wave 4 produces (all global_load_lds, 4-slot
// x 10 KB ring, 3 ahead, counted vmcnt 20/10/0). Best measured: 63.77 us
// total, GEMM 48.3 us, absmax 0. 15 structural variants (deeper pipelines,
// K-split, B-in-LDS, setprio, wider tiles, cross-barrier reg prefetch)
// all measured equal or worse (47-54 us GEMM, 34-39% MfmaUtil plateau).

#define MM 1024
#define NN 11008
#define KK 4096
#define MTILES 8
#define NTILES 86
#define NBLOCKS (MTILES * NTILES)          // 688
#define STRIDE_A ((size_t)MTILES * 8192)   // A2 bytes per kstep (64)
#define STRIDE_B ((size_t)NTILES * 2048)   // B3 bytes per kstep

using i32x4  = __attribute__((ext_vector_type(4))) int;
using i32x16 = __attribute__((ext_vector_type(16))) int;

__device__ __forceinline__ int pack4(i32x4 v) {
    return (int)(((uint32_t)v[0] & 0xFFu) | (((uint32_t)v[1] & 0xFFu) << 8)
               | (((uint32_t)v[2] & 0xFFu) << 16) | (((uint32_t)v[3] & 0xFFu) << 24));
}

// Fused prepass. Blocks [0,1024): A; [1024,3776): B.
// A2: [kstep][mtile][row32][kk2][lane]*16B; data: row = mtile*128 + row32*32
//     + (lane&31), kbyte = kstep*64 + kk2*32 + (lane>>5)*16.
// B3: [kstep][ntile][hf][lane]*16B, dword q = ni*2+kk2 = packed bytes of row
//     n = ntile*128+hf*64+ni*32+(lane&31) at int32 off kstep*16+kk2*8+(lane>>5)*4.
__global__ __launch_bounds__(256) void prep_AB(const int* __restrict__ Asrc,
                                               const int* __restrict__ Bsrc,
                                               uint8_t* __restrict__ A2,
                                               uint8_t* __restrict__ B3) {
    if (blockIdx.x < 1024) {
        const int g = blockIdx.x * 256 + threadIdx.x;    // < 262144
        const int kstep = g >> 12;
        const int rem   = g & 4095;
        const int mtile = rem >> 9;
        const int c     = rem & 511;
        const int row32 = (c >> 7) & 3, kk2 = (c >> 6) & 1;
        const int lane  = c & 63;
        const int row   = mtile * 128 + row32 * 32 + (lane & 31);
        const int kbyte = kstep * 64 + kk2 * 32 + (lane >> 5) * 16;
        const i32x4* s4 = (const i32x4*)(Asrc + (size_t)row * KK + kbyte);
        i32x4 o;
#pragma unroll
        for (int q = 0; q < 4; ++q) o[q] = pack4(s4[q]);
        *(i32x4*)(A2 + (size_t)g * 16) = o;
    } else {
        const int t = (blockIdx.x - 1024) * 256 + threadIdx.x;   // < 704512
        const int n = t >> 6, kstep = t & 63;
        const int ntile = n >> 7, hf = (n >> 6) & 1, ni = (n >> 5) & 1, l31 = n & 31;
        const i32x4* s4 = (const i32x4*)(Bsrc + (size_t)n * (KK / 4) + kstep * 16);
        int w[4];                       // j = kk2*2 + h
#pragma unroll
        for (int j = 0; j < 4; ++j) w[j] = pack4(s4[j]);
        uint8_t* base = B3 + ((size_t)kstep * NTILES + ntile) * 2048 + hf * 1024;
        *(int2*)(base + l31 * 16 + ni * 8)        = make_int2(w[0], w[2]);  // h=0
        *(int2*)(base + (l31 + 32) * 16 + ni * 8) = make_int2(w[1], w[3]);  // h=1
    }
}

#define GLOAD_LDS16(g, l) __builtin_amdgcn_global_load_lds(                    \
        (const __attribute__((address_space(1))) uint32_t*)(g),                \
        (__attribute__((address_space(3))) uint32_t*)(l), 16, 0, 0)

#define MFMA_I8 __builtin_amdgcn_mfma_i32_32x32x32_i8

// Producer: stage K-step T into slot T&3 (A 8 KB = 8 instrs, B 2 KB = 2).
// Slot layout: [0,8192) = A ([row32][kk2][lane]), [8192,10240) = B ([hf][lane]).
#define PSTAGE(T) do {                                                         \
    const uint8_t* at_ = gA + (size_t)(T) * STRIDE_A;                          \
    const uint8_t* bt_ = gB + (size_t)(T) * STRIDE_B;                          \
    uint8_t* l_ = &As[(T) & 3][0];                                             \
    GLOAD_LDS16(at_,        l_);                                               \
    GLOAD_LDS16(at_ + 1024, l_ + 1024);                                        \
    GLOAD_LDS16(at_ + 2048, l_ + 2048);                                        \
    GLOAD_LDS16(at_ + 3072, l_ + 3072);                                        \
    GLOAD_LDS16(at_ + 4096, l_ + 4096);                                        \
    GLOAD_LDS16(at_ + 5120, l_ + 5120);                                        \
    GLOAD_LDS16(at_ + 6144, l_ + 6144);                                        \
    GLOAD_LDS16(at_ + 7168, l_ + 7168);                                        \
    GLOAD_LDS16(bt_,        l_ + 8192);                                        \
    GLOAD_LDS16(bt_ + 1024, l_ + 9216);                                        \
} while (0)

// Consumer: 8 MFMA from slot T&3 (4 A + 1 B ds_read_b128, decode in-reg).
#define COMP(T) do {                                                           \
    const uint8_t* ab_ = &As[(T) & 3][0];                                      \
    i32x4 aA0_ = *(const i32x4*)(ab_ + (wr * 2 + 0) * 2048 + lane * 16);       \
    i32x4 aA1_ = *(const i32x4*)(ab_ + (wr * 2 + 0) * 2048 + 1024 + lane * 16);\
    i32x4 aB0_ = *(const i32x4*)(ab_ + (wr * 2 + 1) * 2048 + lane * 16);       \
    i32x4 aB1_ = *(const i32x4*)(ab_ + (wr * 2 + 1) * 2048 + 1024 + lane * 16);\
    const i32x4 bv_ = *(const i32x4*)(ab_ + 8192 + wc * 1024 + lane * 16);     \
    _Pragma("unroll")                                                          \
    for (int kk2_ = 0; kk2_ < 2; ++kk2_) {                                     \
        const uint32_t q0_ = (uint32_t)bv_[kk2_];                              \
        const uint32_t q1_ = (uint32_t)bv_[2 + kk2_];                          \
        i32x4 b0_, b1_;                                                        \
        _Pragma("unroll")                                                      \
        for (int i_ = 0; i_ < 4; ++i_) {                                       \
            b0_[i_] = (int)((q0_ >> (2 * i_)) & 0x03030303u);                  \
            b1_[i_] = (int)((q1_ >> (2 * i_)) & 0x03030303u);                  \
        }                                                                      \
        const i32x4 am0_ = kk2_ ? aA1_ : aA0_;                                 \
        const i32x4 am1_ = kk2_ ? aB1_ : aB0_;                                 \
        acc[0][0] = MFMA_I8(am0_, b0_, acc[0][0], 0, 0, 0);                    \
        acc[0][1] = MFMA_I8(am0_, b1_, acc[0][1], 0, 0, 0);                    \
        acc[1][0] = MFMA_I8(am1_, b0_, acc[1][0], 0, 0, 0);                    \
        acc[1][1] = MFMA_I8(am1_, b1_, acc[1][1], 0, 0, 0);                    \
    }                                                                          \
} while (0)

#define PWAIT(N) asm volatile("s_waitcnt vmcnt(" #N ")" ::: "memory")

__global__ __launch_bounds__(320, 3) void bitnet_gemm(const uint8_t* __restrict__ A2,
                                                      const uint8_t* __restrict__ B3,
                                                      int* __restrict__ C) {
    const int tid  = threadIdx.x;
    const int lane = tid & 63, wave = tid >> 6;   // waves 0-3 consume, 4 produces
    const int wr   = (wave >> 1) & 1, wc = wave & 1;
    const int l31  = lane & 31, h = lane >> 5;

    // bijective XCD swizzle (688 = 8*86), bm fastest within an XCD chunk.
    const int bid = blockIdx.x;
    const int l   = (bid & 7) * (NBLOCKS / 8) + (bid >> 3);
    const int bm  = l & 7;       // 128-row tile 0..7
    const int bn  = l >> 3;      // 128-col tile 0..85

    __shared__ __align__(16) uint8_t As[4][10240];   // 40 KiB ring

    if (wave == 4) {
        // ---------------- producer ----------------
        const uint8_t* gA = A2 + (size_t)bm * 8192 + lane * 16;
        const uint8_t* gB = B3 + (size_t)bn * 2048 + lane * 16;

        PSTAGE(0); PSTAGE(1); PSTAGE(2);   // 30 outstanding
        PWAIT(20);                         // slot 0 resident
#pragma unroll 1
        for (int t = 0; t < 60; t += 4) {
            // steady state: barrier B_T; issue stage(T+3); wait -> slot T+1
            __builtin_amdgcn_s_barrier(); PSTAGE(t + 3); PWAIT(20);
            __builtin_amdgcn_s_barrier(); PSTAGE(t + 4); PWAIT(20);
            __builtin_amdgcn_s_barrier(); PSTAGE(t + 5); PWAIT(20);
            __builtin_amdgcn_s_barrier(); PSTAGE(t + 6); PWAIT(20);
        }
        __builtin_amdgcn_s_barrier(); PSTAGE(63); PWAIT(20);  // T=60
        __builtin_amdgcn_s_barrier(); PWAIT(10);              // T=61 -> slot 62
        __builtin_amdgcn_s_barrier(); PWAIT(0);               // T=62 -> slot 63
        __builtin_amdgcn_s_barrier();                         // T=63
        return;
    }

    // ---------------- consumers ----------------
    i32x16 acc[2][2] = {};

#pragma unroll 1
    for (int t = 0; t < 64; t += 4) {
        __builtin_amdgcn_s_barrier();
        __builtin_amdgcn_sched_barrier(0);
        COMP(t + 0);
        __builtin_amdgcn_s_barrier();
        __builtin_amdgcn_sched_barrier(0);
        COMP(t + 1);
        __builtin_amdgcn_s_barrier();
        __builtin_amdgcn_sched_barrier(0);
        COMP(t + 2);
        __builtin_amdgcn_s_barrier();
        __builtin_amdgcn_sched_barrier(0);
        COMP(t + 3);
    }

    // C write: col = lane&31, row = (r&3) + 8*(r>>2) + 4*(lane>>5)
    const int brow = bm * 128, bcol = bn * 128;
#pragma unroll
    for (int mi = 0; mi < 2; ++mi)
#pragma unroll
        for (int ni = 0; ni < 2; ++ni) {
            const int colg = bcol + wc * 64 + ni * 32 + l31;
#pragma unroll
            for (int r = 0; r < 16; ++r) {
                const int rowin = (r & 3) + 8 * (r >> 2) + 4 * h;
                const int rowg  = brow + wr * 64 + mi * 32 + rowin;
                C[(size_t)rowg * NN + colg] = acc[mi][ni][r];
            }
        }
}

extern "C" void kernel_launch(void* const* d_in, const int* in_sizes, int n_in,
                              void* d_out, int out_size, void* d_ws, size_t ws_size,
                              hipStream_t stream) {
    const int* A32 = (const int*)d_in[0];   // [M,K] int8 values in int32
    const int* B32 = (const int*)d_in[1];   // [N,K/4] packed bytes in int32
    int* C = (int*)d_out;                   // [M,N] int32

    uint8_t* A2 = (uint8_t*)d_ws;                      // 4 MiB
    uint8_t* B3 = A2 + (size_t)MM * KK;                // 10.75 MiB

    prep_AB<<<dim3(1024 + 2752), dim3(256), 0, stream>>>(A32, B32, A2, B3);
    bitnet_gemm<<<dim3(NBLOCKS), dim3(320), 0, stream>>>(A2, B3, C);
}